// Round 1
// baseline (756.237 us; speedup 1.0000x reference)
//
#include <hip/hip_runtime.h>
#include <cstdint>
#include <cstddef>

#define BB 32
#define NN 1024
#define CIN 128
#define FF 64
#define NOUT 10
#define CAP 128
#define EPSV 1e-5f

// ---------------- CSR build: one pass over A ----------------
// wave per row; float4 loads; ballot prefix-compaction keeps ascending j order
__global__ __launch_bounds__(256) void k_csr(const float* __restrict__ A,
                                             unsigned short* __restrict__ adj,
                                             int* __restrict__ cnt) {
    int wave = threadIdx.x >> 6;
    int lane = threadIdx.x & 63;
    int r = blockIdx.x * 4 + wave;            // global row in [0, B*N)
    const float4* Arow = (const float4*)(A + (size_t)r * NN);
    size_t base = (size_t)r * CAP;
    int c = 0;
    unsigned long long lt = (lane == 0) ? 0ULL : ((1ULL << lane) - 1ULL);
    for (int it = 0; it < 4; ++it) {
        float4 v = Arow[it * 64 + lane];
        int j0 = it * 256 + lane * 4;
        unsigned long long m0 = __ballot(v.x != 0.f);
        unsigned long long m1 = __ballot(v.y != 0.f);
        unsigned long long m2 = __ballot(v.z != 0.f);
        unsigned long long m3 = __ballot(v.w != 0.f);
        int before = __popcll(m0 & lt) + __popcll(m1 & lt) +
                     __popcll(m2 & lt) + __popcll(m3 & lt);
        int p = c + before;
        if (v.x != 0.f) { if (p < CAP) adj[base + p] = (unsigned short)(j0 + 0); ++p; }
        if (v.y != 0.f) { if (p < CAP) adj[base + p] = (unsigned short)(j0 + 1); ++p; }
        if (v.z != 0.f) { if (p < CAP) adj[base + p] = (unsigned short)(j0 + 2); ++p; }
        if (v.w != 0.f) { if (p < CAP) adj[base + p] = (unsigned short)(j0 + 3); ++p; }
        c += __popcll(m0) + __popcll(m1) + __popcll(m2) + __popcll(m3);
    }
    if (lane == 0) cnt[r] = (c > CAP) ? CAP : c;
}

// ---------------- layer-1 coefs: D from raw counts (A pre-masked) ----------------
__global__ __launch_bounds__(256) void k_prep1(const int* __restrict__ cnt,
                                               float* __restrict__ c1, float* __restrict__ c2) {
    int r = blockIdx.x * 256 + threadIdx.x;
    float D = 1.0f / sqrtf((float)cnt[r] + 1.0f + EPSV);
    c1[r] = D;
    c2[r] = D * D;
}

// ---------------- layer-2/3 coefs: masked degree ----------------
__global__ __launch_bounds__(256) void k_deg(const unsigned short* __restrict__ adj,
                                             const int* __restrict__ cnt,
                                             const float* __restrict__ nm,
                                             float* __restrict__ c1, float* __restrict__ c2) {
    int r = blockIdx.x * 256 + threadIdx.x;
    int b = r >> 10;
    size_t base = (size_t)r * CAP;
    int n = cnt[r];
    const float* nmb = nm + (b << 10);
    float s = 0.f;
    for (int t = 0; t < n; ++t) s += nmb[adj[base + t]];
    float m = nm[r];
    float D = 1.0f / sqrtf(m * s + 1.0f + EPSV);
    c1[r] = m * D;
    c2[r] = D * D;
}

// ---------------- x @ W  (no bias; bias added post-SpMM) ----------------
template<int K>
__global__ __launch_bounds__(256) void k_gemm(const float* __restrict__ Xin,
                                              const float* __restrict__ W,
                                              float* __restrict__ T) {
    __shared__ __align__(16) float Wl[K * 64];
    __shared__ float xl[16][K + 1];
    int tid = threadIdx.x;
    for (int t = tid; t < K * 64; t += 256) Wl[t] = W[t];
    int row0 = blockIdx.x * 16;
    for (int t = tid; t < 16 * K; t += 256) {
        int rr = t / K, kk = t % K;
        xl[rr][kk] = Xin[(size_t)(row0 + rr) * K + kk];
    }
    __syncthreads();
    int wave = tid >> 6, lane = tid & 63;
    int rsub = lane >> 4, f0 = (lane & 15) * 4;
    int r = wave * 4 + rsub;
    float4 acc = {0.f, 0.f, 0.f, 0.f};
    const float* xr = xl[r];
#pragma unroll 8
    for (int k = 0; k < K; ++k) {
        float xv = xr[k];
        float4 w4 = *(const float4*)&Wl[k * 64 + f0];
        acc.x += xv * w4.x; acc.y += xv * w4.y;
        acc.z += xv * w4.z; acc.w += xv * w4.w;
    }
    *(float4*)&T[(size_t)(row0 + r) * 64 + f0] = acc;
}

// ---------------- SpMM + self + bias + relu ----------------
__global__ __launch_bounds__(256) void k_spmm(const unsigned short* __restrict__ adj,
                                              const int* __restrict__ cnt,
                                              const float* __restrict__ c1,
                                              const float* __restrict__ c2,
                                              const float* __restrict__ T,
                                              const float* __restrict__ bias,
                                              float* __restrict__ X) {
    int wave = threadIdx.x >> 6, lane = threadIdx.x & 63;
    int r = blockIdx.x * 4 + wave;
    int b = r >> 10;
    size_t base = (size_t)r * CAP;
    int n = cnt[r];
    const float* Tb = T + ((size_t)(b << 10) << 6);
    const float* c1b = c1 + (b << 10);
    float acc = 0.f;
    for (int t = 0; t < n; ++t) {
        int j = adj[base + t];
        acc += c1b[j] * Tb[(j << 6) + lane];
    }
    float o = c1[r] * acc + c2[r] * T[((size_t)r << 6) + lane] + bias[lane];
    X[((size_t)r << 6) + lane] = fmaxf(o, 0.f);
}

// ---------------- pool scores: y = (x . p) / ||p|| ----------------
__global__ __launch_bounds__(256) void k_score(const float* __restrict__ X,
                                               const float* __restrict__ p,
                                               float* __restrict__ y) {
    int wave = threadIdx.x >> 6, lane = threadIdx.x & 63;
    int r = blockIdx.x * 4 + wave;
    float pv = p[lane];
    float a = X[((size_t)r << 6) + lane] * pv;
    float pp = pv * pv;
    for (int s = 32; s; s >>= 1) {
        a += __shfl_xor(a, s, 64);
        pp += __shfl_xor(pp, s, 64);
    }
    if (lane == 0) y[r] = a / sqrtf(pp);
}

// ---------------- pool ranking: stable-argsort semantics, O(N^2) in LDS ----------------
__global__ __launch_bounds__(256) void k_rank(const float* __restrict__ y,
                                              const float* __restrict__ maskSrc,
                                              const int* __restrict__ nsrc,
                                              float* __restrict__ nmOut,
                                              int* __restrict__ ncur) {
    __shared__ float yv[NN];
    __shared__ int s_nrem;
    int b = blockIdx.x;
    int tid = threadIdx.x;
    for (int i = tid; i < NN; i += 256) {
        float m = maskSrc[(b << 10) + i];
        float v = y[(b << 10) + i];
        yv[i] = (m > 0.f) ? v : __builtin_inff();
    }
    if (tid == 0) {
        int n = nsrc[b];
        const float RM = (float)(1.0 - 0.8);   // 0.200000003f, matches jax f32 semantics
        int nr = (int)((float)n * RM);
        s_nrem = nr;
        ncur[b] = n - nr;
    }
    __syncthreads();
    int nrem = s_nrem;
    for (int i = tid; i < NN; i += 256) {
        float yi = yv[i];
        float nmv = 0.f;
        if (yi < __builtin_inff()) {           // valid node
            int rank = 0;
            for (int j = 0; j < NN; ++j) {
                float a = yv[j];
                if (a < yi || (a == yi && j < i)) ++rank;
            }
            nmv = (rank >= nrem) ? 1.f : 0.f;
        }
        nmOut[(b << 10) + i] = nmv;
    }
}

// ---------------- x *= tanh(y) * new_mask ----------------
__global__ __launch_bounds__(256) void k_scale(float* __restrict__ X,
                                               const float* __restrict__ y,
                                               const float* __restrict__ nm) {
    int idx = blockIdx.x * 256 + threadIdx.x;
    int r = idx >> 6;
    X[idx] *= tanhf(y[r]) * nm[r];
}

// ---------------- global max over nodes + final fc ----------------
__global__ __launch_bounds__(256) void k_final(const float* __restrict__ X,
                                               const float* __restrict__ Wfc,
                                               const float* __restrict__ bfc,
                                               float* __restrict__ out) {
    __shared__ float red[4][64];
    __shared__ float gl[64];
    int b = blockIdx.x, tid = threadIdx.x;
    int f = tid & 63, c = tid >> 6;
    float m = 0.f;  // all values are post-relu >= 0
    for (int i = c; i < NN; i += 4)
        m = fmaxf(m, X[(((size_t)(b << 10) + i) << 6) + f]);
    red[c][f] = m;
    __syncthreads();
    if (tid < 64)
        gl[tid] = fmaxf(fmaxf(red[0][tid], red[1][tid]), fmaxf(red[2][tid], red[3][tid]));
    __syncthreads();
    if (tid < NOUT) {
        float acc = bfc[tid];
        for (int k = 0; k < 64; ++k) acc += gl[k] * Wfc[k * NOUT + tid];
        out[b * NOUT + tid] = acc;
    }
}

extern "C" void kernel_launch(void* const* d_in, const int* in_sizes, int n_in,
                              void* d_out, int out_size, void* d_ws, size_t ws_size,
                              hipStream_t stream) {
    const float* x    = (const float*)d_in[0];
    const float* A    = (const float*)d_in[1];
    const float* mask = (const float*)d_in[2];
    const int*   Nn   = (const int*)d_in[3];
    const float* W0   = (const float*)d_in[4];
    const float* b0   = (const float*)d_in[5];
    const float* W1   = (const float*)d_in[6];
    const float* b1   = (const float*)d_in[7];
    const float* W2   = (const float*)d_in[8];
    const float* b2   = (const float*)d_in[9];
    const float* p0   = (const float*)d_in[10];
    const float* p1   = (const float*)d_in[11];
    const float* Wfc  = (const float*)d_in[12];
    const float* bfc  = (const float*)d_in[13];
    float* out = (float*)d_out;

    char* ws = (char*)d_ws;
    size_t off = 0;
    auto alloc = [&](size_t bytes) -> void* {
        void* p = ws + off;
        off = (off + bytes + 255) & ~(size_t)255;
        return p;
    };
    unsigned short* adj = (unsigned short*)alloc((size_t)BB * NN * CAP * 2);
    int*   cnt  = (int*)  alloc((size_t)BB * NN * 4);
    float* X    = (float*)alloc((size_t)BB * NN * 64 * 4);
    float* T    = (float*)alloc((size_t)BB * NN * 64 * 4);
    float* c1   = (float*)alloc((size_t)BB * NN * 4);
    float* c2   = (float*)alloc((size_t)BB * NN * 4);
    float* y    = (float*)alloc((size_t)BB * NN * 4);
    float* nm   = (float*)alloc((size_t)BB * NN * 4);
    int*   ncur = (int*)  alloc((size_t)BB * 4);

    const int RW = BB * NN;       // 32768 rows
    // 1) CSR build (single pass over A)
    k_csr<<<RW / 4, 256, 0, stream>>>(A, adj, cnt);
    // 2) layer 1
    k_prep1<<<RW / 256, 256, 0, stream>>>(cnt, c1, c2);
    k_gemm<128><<<RW / 16, 256, 0, stream>>>(x, W0, T);
    k_spmm<<<RW / 4, 256, 0, stream>>>(adj, cnt, c1, c2, T, b0, X);
    // pool 1
    k_score<<<RW / 4, 256, 0, stream>>>(X, p0, y);
    k_rank<<<BB, 256, 0, stream>>>(y, mask, Nn, nm, ncur);
    k_scale<<<RW * 64 / 256, 256, 0, stream>>>(X, y, nm);
    // 3) layer 2
    k_deg<<<RW / 256, 256, 0, stream>>>(adj, cnt, nm, c1, c2);
    k_gemm<64><<<RW / 16, 256, 0, stream>>>(X, W1, T);
    k_spmm<<<RW / 4, 256, 0, stream>>>(adj, cnt, c1, c2, T, b1, X);
    // pool 2 (in-place mask/ncur update is safe: LDS-staged before writes)
    k_score<<<RW / 4, 256, 0, stream>>>(X, p1, y);
    k_rank<<<BB, 256, 0, stream>>>(y, nm, ncur, nm, ncur);
    k_scale<<<RW * 64 / 256, 256, 0, stream>>>(X, y, nm);
    // 4) layer 3
    k_deg<<<RW / 256, 256, 0, stream>>>(adj, cnt, nm, c1, c2);
    k_gemm<64><<<RW / 16, 256, 0, stream>>>(X, W2, T);
    k_spmm<<<RW / 4, 256, 0, stream>>>(adj, cnt, c1, c2, T, b2, X);
    // 5) global max pool + fc
    k_final<<<BB, 256, 0, stream>>>(X, Wfc, bfc, out);
}

// Round 2
// 553.519 us; speedup vs baseline: 1.3662x; 1.3662x over previous
//
#include <hip/hip_runtime.h>
#include <cstdint>
#include <cstddef>

#define BB 32
#define NN 1024
#define CIN 128
#define FF 64
#define NOUT 10
#define CAP 128
#define EPSV 1e-5f

// ---------------- CSR build + layer-1 coefs: one pass over A ----------------
// wave per row; float4 loads; ballot prefix-compaction keeps ascending j order
__global__ __launch_bounds__(256) void k_csr(const float* __restrict__ A,
                                             unsigned short* __restrict__ adj,
                                             int* __restrict__ cnt,
                                             float* __restrict__ c1,
                                             float* __restrict__ c2) {
    int wave = threadIdx.x >> 6;
    int lane = threadIdx.x & 63;
    int r = blockIdx.x * 4 + wave;            // global row in [0, B*N)
    const float4* Arow = (const float4*)(A + (size_t)r * NN);
    size_t base = (size_t)r * CAP;
    int c = 0;
    unsigned long long lt = (lane == 0) ? 0ULL : ((1ULL << lane) - 1ULL);
    for (int it = 0; it < 4; ++it) {
        float4 v = Arow[it * 64 + lane];
        int j0 = it * 256 + lane * 4;
        unsigned long long m0 = __ballot(v.x != 0.f);
        unsigned long long m1 = __ballot(v.y != 0.f);
        unsigned long long m2 = __ballot(v.z != 0.f);
        unsigned long long m3 = __ballot(v.w != 0.f);
        int before = __popcll(m0 & lt) + __popcll(m1 & lt) +
                     __popcll(m2 & lt) + __popcll(m3 & lt);
        int p = c + before;
        if (v.x != 0.f) { if (p < CAP) adj[base + p] = (unsigned short)(j0 + 0); ++p; }
        if (v.y != 0.f) { if (p < CAP) adj[base + p] = (unsigned short)(j0 + 1); ++p; }
        if (v.z != 0.f) { if (p < CAP) adj[base + p] = (unsigned short)(j0 + 2); ++p; }
        if (v.w != 0.f) { if (p < CAP) adj[base + p] = (unsigned short)(j0 + 3); ++p; }
        c += __popcll(m0) + __popcll(m1) + __popcll(m2) + __popcll(m3);
    }
    if (lane == 0) {
        cnt[r] = (c > CAP) ? CAP : c;
        // layer-1 degree uses the uncapped row sum (A is pre-masked, entries are 1.0)
        float D = 1.0f / sqrtf((float)c + 1.0f + EPSV);
        c1[r] = D;
        c2[r] = D * D;
    }
}

// ---------------- layer-2/3 coefs: masked degree ----------------
__global__ __launch_bounds__(256) void k_deg(const unsigned short* __restrict__ adj,
                                             const int* __restrict__ cnt,
                                             const float* __restrict__ nm,
                                             float* __restrict__ c1, float* __restrict__ c2) {
    int r = blockIdx.x * 256 + threadIdx.x;
    int b = r >> 10;
    size_t base = (size_t)r * CAP;
    int n = cnt[r];
    const float* nmb = nm + (b << 10);
    float s = 0.f;
    for (int t = 0; t < n; ++t) s += nmb[adj[base + t]];
    float m = nm[r];
    float D = 1.0f / sqrtf(m * s + 1.0f + EPSV);
    c1[r] = m * D;
    c2[r] = D * D;
}

// ---------------- x @ W  (optionally scale x rows by tanh(y)*nm on load) ----------------
template<int K, bool SCALED>
__global__ __launch_bounds__(256) void k_gemm(const float* __restrict__ Xin,
                                              const float* __restrict__ W,
                                              const float* __restrict__ y,
                                              const float* __restrict__ nm,
                                              float* __restrict__ T) {
    __shared__ __align__(16) float Wl[K * 64];
    __shared__ float xl[16][K + 1];
    __shared__ float sscale[16];
    int tid = threadIdx.x;
    int row0 = blockIdx.x * 16;
    if (SCALED && tid < 16) {
        int r = row0 + tid;
        sscale[tid] = tanhf(y[r]) * nm[r];
    }
    for (int t = tid; t < K * 64; t += 256) Wl[t] = W[t];
    __syncthreads();
    for (int t = tid; t < 16 * K; t += 256) {
        int rr = t / K, kk = t % K;
        float v = Xin[(size_t)(row0 + rr) * K + kk];
        xl[rr][kk] = SCALED ? v * sscale[rr] : v;
    }
    __syncthreads();
    int wave = tid >> 6, lane = tid & 63;
    int rsub = lane >> 4, f0 = (lane & 15) * 4;
    int r = wave * 4 + rsub;
    float4 acc = {0.f, 0.f, 0.f, 0.f};
    const float* xr = xl[r];
#pragma unroll 8
    for (int k = 0; k < K; ++k) {
        float xv = xr[k];
        float4 w4 = *(const float4*)&Wl[k * 64 + f0];
        acc.x += xv * w4.x; acc.y += xv * w4.y;
        acc.z += xv * w4.z; acc.w += xv * w4.w;
    }
    *(float4*)&T[(size_t)(row0 + r) * 64 + f0] = acc;
}

// ---------------- SpMM + self + bias + relu (+ fused pool score) ----------------
__global__ __launch_bounds__(256) void k_spmm(const unsigned short* __restrict__ adj,
                                              const int* __restrict__ cnt,
                                              const float* __restrict__ c1,
                                              const float* __restrict__ c2,
                                              const float* __restrict__ T,
                                              const float* __restrict__ bias,
                                              float* __restrict__ X,
                                              const float* __restrict__ p,
                                              float* __restrict__ y) {
    int wave = threadIdx.x >> 6, lane = threadIdx.x & 63;
    int r = blockIdx.x * 4 + wave;
    int b = r >> 10;
    size_t base = (size_t)r * CAP;
    int n = cnt[r];
    const float* Tb = T + ((size_t)(b << 10) << 6);
    const float* c1b = c1 + (b << 10);
    float acc = 0.f;
    for (int t = 0; t < n; ++t) {
        int j = adj[base + t];
        acc += c1b[j] * Tb[(j << 6) + lane];
    }
    float o = c1[r] * acc + c2[r] * T[((size_t)r << 6) + lane] + bias[lane];
    o = fmaxf(o, 0.f);
    X[((size_t)r << 6) + lane] = o;
    if (p != nullptr) {
        float pv = p[lane];
        float a = o * pv;
        float pp = pv * pv;
        for (int s = 32; s; s >>= 1) {
            a += __shfl_xor(a, s, 64);
            pp += __shfl_xor(pp, s, 64);
        }
        if (lane == 0) y[r] = a / sqrtf(pp);
    }
}

// ---------------- pool ranking: stable-argsort semantics, 16 blocks/graph ----------------
__global__ __launch_bounds__(256) void k_rank(const float* __restrict__ y,
                                              const float* __restrict__ maskSrc,
                                              const int* __restrict__ nsrc,
                                              float* __restrict__ nmOut,
                                              int* __restrict__ ncur) {
    __shared__ __align__(16) float yv[NN];
    int b = blockIdx.x >> 4;       // 16 blocks per graph
    int sub = blockIdx.x & 15;
    int tid = threadIdx.x;
    const float INF = __builtin_inff();
    {
        float4 v = ((const float4*)(y + (b << 10)))[tid];
        float4 m = ((const float4*)(maskSrc + (b << 10)))[tid];
        v.x = (m.x > 0.f) ? v.x : INF;
        v.y = (m.y > 0.f) ? v.y : INF;
        v.z = (m.z > 0.f) ? v.z : INF;
        v.w = (m.w > 0.f) ? v.w : INF;
        ((float4*)yv)[tid] = v;
    }
    int n = nsrc[b];
    const float RM = (float)(1.0 - 0.8);   // 0.2f, matches jax f32 semantics
    int nrem = (int)((float)n * RM);
    if (sub == 0 && tid == 0) ncur[b] = n - nrem;
    __syncthreads();
    int i = (sub << 6) + (tid >> 2);       // 64 nodes per block, 4 threads per node
    int q = tid & 3;                       // quarter of the j-range
    float yi = yv[i];
    int rank = 0;
    if (yi < INF) {
        const float4* jbase = (const float4*)yv + (q << 6);
        int j0 = q << 8;
#pragma unroll 8
        for (int t = 0; t < 64; ++t) {
            float4 a = jbase[t];
            int j = j0 + t * 4;
            rank += (a.x < yi || (a.x == yi && j     < i)) ? 1 : 0;
            rank += (a.y < yi || (a.y == yi && j + 1 < i)) ? 1 : 0;
            rank += (a.z < yi || (a.z == yi && j + 2 < i)) ? 1 : 0;
            rank += (a.w < yi || (a.w == yi && j + 3 < i)) ? 1 : 0;
        }
    }
    rank += __shfl_xor(rank, 1, 64);
    rank += __shfl_xor(rank, 2, 64);
    if (q == 0) {
        float nmv = (yi < INF && rank >= nrem) ? 1.f : 0.f;
        nmOut[(b << 10) + i] = nmv;
    }
}

// ---------------- global max over nodes + final fc ----------------
__global__ __launch_bounds__(256) void k_final(const float* __restrict__ X,
                                               const float* __restrict__ Wfc,
                                               const float* __restrict__ bfc,
                                               float* __restrict__ out) {
    __shared__ float red[4][64];
    __shared__ float gl[64];
    int b = blockIdx.x, tid = threadIdx.x;
    int f = tid & 63, c = tid >> 6;
    float m = 0.f;  // all values are post-relu >= 0
    for (int i = c; i < NN; i += 4)
        m = fmaxf(m, X[(((size_t)(b << 10) + i) << 6) + f]);
    red[c][f] = m;
    __syncthreads();
    if (tid < 64)
        gl[tid] = fmaxf(fmaxf(red[0][tid], red[1][tid]), fmaxf(red[2][tid], red[3][tid]));
    __syncthreads();
    if (tid < NOUT) {
        float acc = bfc[tid];
        for (int k = 0; k < 64; ++k) acc += gl[k] * Wfc[k * NOUT + tid];
        out[b * NOUT + tid] = acc;
    }
}

extern "C" void kernel_launch(void* const* d_in, const int* in_sizes, int n_in,
                              void* d_out, int out_size, void* d_ws, size_t ws_size,
                              hipStream_t stream) {
    const float* x    = (const float*)d_in[0];
    const float* A    = (const float*)d_in[1];
    const float* mask = (const float*)d_in[2];
    const int*   Nn   = (const int*)d_in[3];
    const float* W0   = (const float*)d_in[4];
    const float* b0   = (const float*)d_in[5];
    const float* W1   = (const float*)d_in[6];
    const float* b1   = (const float*)d_in[7];
    const float* W2   = (const float*)d_in[8];
    const float* b2   = (const float*)d_in[9];
    const float* p0   = (const float*)d_in[10];
    const float* p1   = (const float*)d_in[11];
    const float* Wfc  = (const float*)d_in[12];
    const float* bfc  = (const float*)d_in[13];
    float* out = (float*)d_out;

    char* ws = (char*)d_ws;
    size_t off = 0;
    auto alloc = [&](size_t bytes) -> void* {
        void* p = ws + off;
        off = (off + bytes + 255) & ~(size_t)255;
        return p;
    };
    unsigned short* adj = (unsigned short*)alloc((size_t)BB * NN * CAP * 2);
    int*   cnt  = (int*)  alloc((size_t)BB * NN * 4);
    float* X    = (float*)alloc((size_t)BB * NN * 64 * 4);
    float* T    = (float*)alloc((size_t)BB * NN * 64 * 4);
    float* c1   = (float*)alloc((size_t)BB * NN * 4);
    float* c2   = (float*)alloc((size_t)BB * NN * 4);
    float* y    = (float*)alloc((size_t)BB * NN * 4);
    float* nm0  = (float*)alloc((size_t)BB * NN * 4);
    float* nm1  = (float*)alloc((size_t)BB * NN * 4);
    int*   nc0  = (int*)  alloc((size_t)BB * 4);
    int*   nc1  = (int*)  alloc((size_t)BB * 4);

    const int RW = BB * NN;       // 32768 rows
    // 1) CSR build + layer-1 coefs (single pass over A)
    k_csr<<<RW / 4, 256, 0, stream>>>(A, adj, cnt, c1, c2);
    // 2) layer 1
    k_gemm<128, false><<<RW / 16, 256, 0, stream>>>(x, W0, nullptr, nullptr, T);
    k_spmm<<<RW / 4, 256, 0, stream>>>(adj, cnt, c1, c2, T, b0, X, p0, y);
    // pool 1 (16 blocks per graph)
    k_rank<<<BB * 16, 256, 0, stream>>>(y, mask, Nn, nm0, nc0);
    // 3) layer 2 (scale fused into gemm load)
    k_deg<<<RW / 256, 256, 0, stream>>>(adj, cnt, nm0, c1, c2);
    k_gemm<64, true><<<RW / 16, 256, 0, stream>>>(X, W1, y, nm0, T);
    k_spmm<<<RW / 4, 256, 0, stream>>>(adj, cnt, c1, c2, T, b1, X, p1, y);
    // pool 2 (double-buffered mask: read nm0, write nm1)
    k_rank<<<BB * 16, 256, 0, stream>>>(y, nm0, nc0, nm1, nc1);
    // 4) layer 3
    k_deg<<<RW / 256, 256, 0, stream>>>(adj, cnt, nm1, c1, c2);
    k_gemm<64, true><<<RW / 16, 256, 0, stream>>>(X, W2, y, nm1, T);
    k_spmm<<<RW / 4, 256, 0, stream>>>(adj, cnt, c1, c2, T, b2, X, nullptr, nullptr);
    // 5) global max pool + fc
    k_final<<<BB, 256, 0, stream>>>(X, Wfc, bfc, out);
}

// Round 3
// 459.582 us; speedup vs baseline: 1.6455x; 1.2044x over previous
//
#include <hip/hip_runtime.h>
#include <cstdint>
#include <cstddef>

#define BB 32
#define NN 1024
#define CIN 128
#define FF 64
#define NOUT 10
#define CAP 128
#define EPSV 1e-5f

// ---------------- fused front: [0,2048) = x@W0 gemm blocks, [2048,10240) = CSR build ----------------
// The two halves are independent; fusing lets the small GEMM hide inside the HBM-bound A scan.
__global__ __launch_bounds__(256) void k_front(const float* __restrict__ A,
                                               const float* __restrict__ x,
                                               const float* __restrict__ W0,
                                               unsigned short* __restrict__ adj,
                                               int* __restrict__ cnt,
                                               float* __restrict__ c1,
                                               float* __restrict__ c2,
                                               float* __restrict__ T) {
    extern __shared__ float smem[];
    int tid = threadIdx.x;
    if (blockIdx.x < 2048) {
        // ---- gemm: T[row, f] = sum_k x[row,k] * W0[k,f], 16 rows per block ----
        float* Wl = smem;                                  // 128*64
        float (*xl)[CIN + 1] = (float (*)[CIN + 1])(smem + CIN * 64);
        for (int t = tid; t < CIN * 64; t += 256) Wl[t] = W0[t];
        int row0 = blockIdx.x * 16;
        for (int t = tid; t < 16 * CIN; t += 256) {
            int rr = t >> 7, kk = t & 127;
            xl[rr][kk] = x[(size_t)(row0 + rr) * CIN + kk];
        }
        __syncthreads();
        int wave = tid >> 6, lane = tid & 63;
        int rsub = lane >> 4, f0 = (lane & 15) * 4;
        int r = wave * 4 + rsub;
        float4 acc = {0.f, 0.f, 0.f, 0.f};
        const float* xr = xl[r];
#pragma unroll 8
        for (int k = 0; k < CIN; ++k) {
            float xv = xr[k];
            float4 w4 = *(const float4*)&Wl[k * 64 + f0];
            acc.x += xv * w4.x; acc.y += xv * w4.y;
            acc.z += xv * w4.z; acc.w += xv * w4.w;
        }
        *(float4*)&T[(size_t)(row0 + r) * 64 + f0] = acc;
    } else {
        // ---- CSR build: wave per row, ballot prefix-compaction (ascending j) ----
        int wave = tid >> 6;
        int lane = tid & 63;
        int r = (blockIdx.x - 2048) * 4 + wave;            // global row in [0, B*N)
        const float4* Arow = (const float4*)(A + (size_t)r * NN);
        size_t base = (size_t)r * CAP;
        int c = 0;
        unsigned long long lt = (lane == 0) ? 0ULL : ((1ULL << lane) - 1ULL);
        for (int it = 0; it < 4; ++it) {
            float4 v = Arow[it * 64 + lane];
            int j0 = it * 256 + lane * 4;
            unsigned long long m0 = __ballot(v.x != 0.f);
            unsigned long long m1 = __ballot(v.y != 0.f);
            unsigned long long m2 = __ballot(v.z != 0.f);
            unsigned long long m3 = __ballot(v.w != 0.f);
            int before = __popcll(m0 & lt) + __popcll(m1 & lt) +
                         __popcll(m2 & lt) + __popcll(m3 & lt);
            int p = c + before;
            if (v.x != 0.f) { if (p < CAP) adj[base + p] = (unsigned short)(j0 + 0); ++p; }
            if (v.y != 0.f) { if (p < CAP) adj[base + p] = (unsigned short)(j0 + 1); ++p; }
            if (v.z != 0.f) { if (p < CAP) adj[base + p] = (unsigned short)(j0 + 2); ++p; }
            if (v.w != 0.f) { if (p < CAP) adj[base + p] = (unsigned short)(j0 + 3); ++p; }
            c += __popcll(m0) + __popcll(m1) + __popcll(m2) + __popcll(m3);
        }
        if (lane == 0) {
            cnt[r] = (c > CAP) ? CAP : c;
            float D = 1.0f / sqrtf((float)c + 1.0f + EPSV);
            c1[r] = D;
            c2[r] = D * D;
        }
    }
}

// ---------------- layer-2/3 coefs: masked degree, wave per row ----------------
// nm entries are 0/1 so the lane-parallel sum is exact regardless of order.
__global__ __launch_bounds__(256) void k_deg(const unsigned short* __restrict__ adj,
                                             const int* __restrict__ cnt,
                                             const float* __restrict__ nm,
                                             float* __restrict__ c1, float* __restrict__ c2) {
    int wave = threadIdx.x >> 6, lane = threadIdx.x & 63;
    int r = blockIdx.x * 4 + wave;
    int b = r >> 10;
    const unsigned short* arow = adj + (size_t)r * CAP;
    const float* nmb = nm + (b << 10);
    int n = cnt[r];
    float s = 0.f;
    if (lane < n)      s  = nmb[arow[lane]];
    if (lane + 64 < n) s += nmb[arow[lane + 64]];
    for (int sh = 32; sh; sh >>= 1) s += __shfl_xor(s, sh, 64);
    if (lane == 0) {
        float m = nm[r];
        float D = 1.0f / sqrtf(m * s + 1.0f + EPSV);
        c1[r] = m * D;
        c2[r] = D * D;
    }
}

// ---------------- x @ W with tanh(y)*nm row scale fused on load ----------------
__global__ __launch_bounds__(256) void k_gemm64(const float* __restrict__ Xin,
                                                const float* __restrict__ W,
                                                const float* __restrict__ y,
                                                const float* __restrict__ nm,
                                                float* __restrict__ T) {
    __shared__ __align__(16) float Wl[64 * 64];
    __shared__ float xl[16][65];
    __shared__ float sscale[16];
    int tid = threadIdx.x;
    int row0 = blockIdx.x * 16;
    if (tid < 16) {
        int r = row0 + tid;
        sscale[tid] = tanhf(y[r]) * nm[r];
    }
    for (int t = tid; t < 64 * 64; t += 256) Wl[t] = W[t];
    __syncthreads();
    for (int t = tid; t < 16 * 64; t += 256) {
        int rr = t >> 6, kk = t & 63;
        xl[rr][kk] = Xin[(size_t)(row0 + rr) * 64 + kk] * sscale[rr];
    }
    __syncthreads();
    int wave = tid >> 6, lane = tid & 63;
    int rsub = lane >> 4, f0 = (lane & 15) * 4;
    int r = wave * 4 + rsub;
    float4 acc = {0.f, 0.f, 0.f, 0.f};
    const float* xr = xl[r];
#pragma unroll 8
    for (int k = 0; k < 64; ++k) {
        float xv = xr[k];
        float4 w4 = *(const float4*)&Wl[k * 64 + f0];
        acc.x += xv * w4.x; acc.y += xv * w4.y;
        acc.z += xv * w4.z; acc.w += xv * w4.w;
    }
    *(float4*)&T[(size_t)(row0 + r) * 64 + f0] = acc;
}

// ---------------- SpMM + self + bias + relu (+ fused pool score) ----------------
// unrolled x4: one ushort4 broadcast load of indices, 4 independent gather/fma chains
__global__ __launch_bounds__(256) void k_spmm(const unsigned short* __restrict__ adj,
                                              const int* __restrict__ cnt,
                                              const float* __restrict__ c1,
                                              const float* __restrict__ c2,
                                              const float* __restrict__ T,
                                              const float* __restrict__ bias,
                                              float* __restrict__ X,
                                              const float* __restrict__ p,
                                              float* __restrict__ y) {
    int wave = threadIdx.x >> 6, lane = threadIdx.x & 63;
    int r = blockIdx.x * 4 + wave;
    int b = r >> 10;
    const unsigned short* arow = adj + (size_t)r * CAP;
    int n = cnt[r];
    const float* Tb = T + ((size_t)(b << 10) << 6);
    const float* c1b = c1 + (b << 10);
    float acc0 = 0.f, acc1 = 0.f, acc2 = 0.f, acc3 = 0.f;
    int t = 0;
    for (; t + 4 <= n; t += 4) {
        ushort4 j4 = *(const ushort4*)(arow + t);
        acc0 += c1b[j4.x] * Tb[((int)j4.x << 6) + lane];
        acc1 += c1b[j4.y] * Tb[((int)j4.y << 6) + lane];
        acc2 += c1b[j4.z] * Tb[((int)j4.z << 6) + lane];
        acc3 += c1b[j4.w] * Tb[((int)j4.w << 6) + lane];
    }
    for (; t < n; ++t) {
        int j = arow[t];
        acc0 += c1b[j] * Tb[(j << 6) + lane];
    }
    float acc = (acc0 + acc1) + (acc2 + acc3);
    float o = c1[r] * acc + c2[r] * T[((size_t)r << 6) + lane] + bias[lane];
    o = fmaxf(o, 0.f);
    X[((size_t)r << 6) + lane] = o;
    if (p != nullptr) {
        float pv = p[lane];
        float a = o * pv;
        float pp = pv * pv;
        for (int s = 32; s; s >>= 1) {
            a += __shfl_xor(a, s, 64);
            pp += __shfl_xor(pp, s, 64);
        }
        if (lane == 0) y[r] = a / sqrtf(pp);
    }
}

// ---------------- pool ranking: stable-argsort semantics, 16 blocks/graph ----------------
__global__ __launch_bounds__(256) void k_rank(const float* __restrict__ y,
                                              const float* __restrict__ maskSrc,
                                              const int* __restrict__ nsrc,
                                              float* __restrict__ nmOut,
                                              int* __restrict__ ncur) {
    __shared__ __align__(16) float yv[NN];
    int b = blockIdx.x >> 4;       // 16 blocks per graph
    int sub = blockIdx.x & 15;
    int tid = threadIdx.x;
    const float INF = __builtin_inff();
    {
        float4 v = ((const float4*)(y + (b << 10)))[tid];
        float4 m = ((const float4*)(maskSrc + (b << 10)))[tid];
        v.x = (m.x > 0.f) ? v.x : INF;
        v.y = (m.y > 0.f) ? v.y : INF;
        v.z = (m.z > 0.f) ? v.z : INF;
        v.w = (m.w > 0.f) ? v.w : INF;
        ((float4*)yv)[tid] = v;
    }
    int n = nsrc[b];
    const float RM = (float)(1.0 - 0.8);   // 0.2f, matches jax f32 semantics
    int nrem = (int)((float)n * RM);
    if (sub == 0 && tid == 0) ncur[b] = n - nrem;
    __syncthreads();
    int i = (sub << 6) + (tid >> 2);       // 64 nodes per block, 4 threads per node
    int q = tid & 3;                       // quarter of the j-range
    float yi = yv[i];
    int rank = 0;
    if (yi < INF) {
        const float4* jbase = (const float4*)yv + (q << 6);
        int j0 = q << 8;
#pragma unroll 8
        for (int t = 0; t < 64; ++t) {
            float4 a = jbase[t];
            int j = j0 + t * 4;
            rank += (a.x < yi || (a.x == yi && j     < i)) ? 1 : 0;
            rank += (a.y < yi || (a.y == yi && j + 1 < i)) ? 1 : 0;
            rank += (a.z < yi || (a.z == yi && j + 2 < i)) ? 1 : 0;
            rank += (a.w < yi || (a.w == yi && j + 3 < i)) ? 1 : 0;
        }
    }
    rank += __shfl_xor(rank, 1, 64);
    rank += __shfl_xor(rank, 2, 64);
    if (q == 0) {
        float nmv = (yi < INF && rank >= nrem) ? 1.f : 0.f;
        nmOut[(b << 10) + i] = nmv;
    }
}

// ---------------- global max over nodes + final fc ----------------
__global__ __launch_bounds__(256) void k_final(const float* __restrict__ X,
                                               const float* __restrict__ Wfc,
                                               const float* __restrict__ bfc,
                                               float* __restrict__ out) {
    __shared__ float red[4][64];
    __shared__ float gl[64];
    int b = blockIdx.x, tid = threadIdx.x;
    int f = tid & 63, c = tid >> 6;
    float m = 0.f;  // all values are post-relu >= 0
    for (int i = c; i < NN; i += 4)
        m = fmaxf(m, X[(((size_t)(b << 10) + i) << 6) + f]);
    red[c][f] = m;
    __syncthreads();
    if (tid < 64)
        gl[tid] = fmaxf(fmaxf(red[0][tid], red[1][tid]), fmaxf(red[2][tid], red[3][tid]));
    __syncthreads();
    if (tid < NOUT) {
        float acc = bfc[tid];
        for (int k = 0; k < 64; ++k) acc += gl[k] * Wfc[k * NOUT + tid];
        out[b * NOUT + tid] = acc;
    }
}

extern "C" void kernel_launch(void* const* d_in, const int* in_sizes, int n_in,
                              void* d_out, int out_size, void* d_ws, size_t ws_size,
                              hipStream_t stream) {
    const float* x    = (const float*)d_in[0];
    const float* A    = (const float*)d_in[1];
    const float* mask = (const float*)d_in[2];
    const int*   Nn   = (const int*)d_in[3];
    const float* W0   = (const float*)d_in[4];
    const float* b0   = (const float*)d_in[5];
    const float* W1   = (const float*)d_in[6];
    const float* b1   = (const float*)d_in[7];
    const float* W2   = (const float*)d_in[8];
    const float* b2   = (const float*)d_in[9];
    const float* p0   = (const float*)d_in[10];
    const float* p1   = (const float*)d_in[11];
    const float* Wfc  = (const float*)d_in[12];
    const float* bfc  = (const float*)d_in[13];
    float* out = (float*)d_out;

    char* ws = (char*)d_ws;
    size_t off = 0;
    auto alloc = [&](size_t bytes) -> void* {
        void* p = ws + off;
        off = (off + bytes + 255) & ~(size_t)255;
        return p;
    };
    unsigned short* adj = (unsigned short*)alloc((size_t)BB * NN * CAP * 2);
    int*   cnt  = (int*)  alloc((size_t)BB * NN * 4);
    float* X    = (float*)alloc((size_t)BB * NN * 64 * 4);
    float* T    = (float*)alloc((size_t)BB * NN * 64 * 4);
    float* c1   = (float*)alloc((size_t)BB * NN * 4);
    float* c2   = (float*)alloc((size_t)BB * NN * 4);
    float* y    = (float*)alloc((size_t)BB * NN * 4);
    float* nm0  = (float*)alloc((size_t)BB * NN * 4);
    float* nm1  = (float*)alloc((size_t)BB * NN * 4);
    int*   nc0  = (int*)  alloc((size_t)BB * 4);
    int*   nc1  = (int*)  alloc((size_t)BB * 4);

    const int RW = BB * NN;       // 32768 rows
    const size_t frontLds = (size_t)(CIN * 64 + 16 * (CIN + 1)) * 4;   // 41 KB
    // 1) fused: x@W0 gemm (2048 blocks) + CSR build + layer-1 coefs (8192 blocks)
    k_front<<<2048 + RW / 4, 256, frontLds, stream>>>(A, x, W0, adj, cnt, c1, c2, T);
    // 2) layer 1 SpMM (+ pool-1 score)
    k_spmm<<<RW / 4, 256, 0, stream>>>(adj, cnt, c1, c2, T, b0, X, p0, y);
    // pool 1 (16 blocks per graph)
    k_rank<<<BB * 16, 256, 0, stream>>>(y, mask, Nn, nm0, nc0);
    // 3) layer 2
    k_deg<<<RW / 4, 256, 0, stream>>>(adj, cnt, nm0, c1, c2);
    k_gemm64<<<RW / 16, 256, 0, stream>>>(X, W1, y, nm0, T);
    k_spmm<<<RW / 4, 256, 0, stream>>>(adj, cnt, c1, c2, T, b1, X, p1, y);
    // pool 2 (double-buffered mask: read nm0, write nm1)
    k_rank<<<BB * 16, 256, 0, stream>>>(y, nm0, nc0, nm1, nc1);
    // 4) layer 3
    k_deg<<<RW / 4, 256, 0, stream>>>(adj, cnt, nm1, c1, c2);
    k_gemm64<<<RW / 16, 256, 0, stream>>>(X, W2, y, nm1, T);
    k_spmm<<<RW / 4, 256, 0, stream>>>(adj, cnt, c1, c2, T, b2, X, nullptr, nullptr);
    // 5) global max pool + fc
    k_final<<<BB, 256, 0, stream>>>(X, Wfc, bfc, out);
}

// Round 4
// 395.168 us; speedup vs baseline: 1.9137x; 1.1630x over previous
//
#include <hip/hip_runtime.h>
#include <cstdint>
#include <cstddef>

#define BB 32
#define NN 1024
#define CIN 128
#define FF 64
#define NOUT 10
#define CAP 128
#define EPSV 1e-5f

// ---------------- fused front: [0,2048) = x@W0 gemm blocks, [2048,10240) = CSR build ----------------
// gemm blocks use blockIdx = c*32 + b so graph b's T rows are written on XCD b%8
__global__ __launch_bounds__(256) void k_front(const float* __restrict__ A,
                                               const float* __restrict__ x,
                                               const float* __restrict__ W0,
                                               unsigned short* __restrict__ adj,
                                               int* __restrict__ cnt,
                                               float* __restrict__ c1,
                                               float* __restrict__ c2,
                                               float* __restrict__ T) {
    extern __shared__ float smem[];
    int tid = threadIdx.x;
    if (blockIdx.x < 2048) {
        // ---- gemm: T[row, f] = sum_k x[row,k] * W0[k,f], 16 rows per block ----
        int b = blockIdx.x & 31;            // graph -> XCD b%8
        int cch = blockIdx.x >> 5;          // chunk in [0,64)
        int row0 = (b << 10) + cch * 16;
        float* Wl = smem;                                  // 128*64
        float (*xl)[CIN + 1] = (float (*)[CIN + 1])(smem + CIN * 64);
        for (int t = tid; t < CIN * 64; t += 256) Wl[t] = W0[t];
        for (int t = tid; t < 16 * CIN; t += 256) {
            int rr = t >> 7, kk = t & 127;
            xl[rr][kk] = x[(size_t)(row0 + rr) * CIN + kk];
        }
        __syncthreads();
        int wave = tid >> 6, lane = tid & 63;
        int rsub = lane >> 4, f0 = (lane & 15) * 4;
        int r = wave * 4 + rsub;
        float4 acc = {0.f, 0.f, 0.f, 0.f};
        const float* xr = xl[r];
#pragma unroll 8
        for (int k = 0; k < CIN; ++k) {
            float xv = xr[k];
            float4 w4 = *(const float4*)&Wl[k * 64 + f0];
            acc.x += xv * w4.x; acc.y += xv * w4.y;
            acc.z += xv * w4.z; acc.w += xv * w4.w;
        }
        *(float4*)&T[(size_t)(row0 + r) * 64 + f0] = acc;
    } else {
        // ---- CSR build: wave per row, ballot prefix-compaction (ascending j) ----
        int wave = tid >> 6;
        int lane = tid & 63;
        int r = (blockIdx.x - 2048) * 4 + wave;            // global row in [0, B*N)
        const float4* Arow = (const float4*)(A + (size_t)r * NN);
        size_t base = (size_t)r * CAP;
        int c = 0;
        unsigned long long lt = (lane == 0) ? 0ULL : ((1ULL << lane) - 1ULL);
        for (int it = 0; it < 4; ++it) {
            float4 v = Arow[it * 64 + lane];
            int j0 = it * 256 + lane * 4;
            unsigned long long m0 = __ballot(v.x != 0.f);
            unsigned long long m1 = __ballot(v.y != 0.f);
            unsigned long long m2 = __ballot(v.z != 0.f);
            unsigned long long m3 = __ballot(v.w != 0.f);
            int before = __popcll(m0 & lt) + __popcll(m1 & lt) +
                         __popcll(m2 & lt) + __popcll(m3 & lt);
            int p = c + before;
            if (v.x != 0.f) { if (p < CAP) adj[base + p] = (unsigned short)(j0 + 0); ++p; }
            if (v.y != 0.f) { if (p < CAP) adj[base + p] = (unsigned short)(j0 + 1); ++p; }
            if (v.z != 0.f) { if (p < CAP) adj[base + p] = (unsigned short)(j0 + 2); ++p; }
            if (v.w != 0.f) { if (p < CAP) adj[base + p] = (unsigned short)(j0 + 3); ++p; }
            c += __popcll(m0) + __popcll(m1) + __popcll(m2) + __popcll(m3);
        }
        if (lane == 0) {
            cnt[r] = (c > CAP) ? CAP : c;
            float D = 1.0f / sqrtf((float)c + 1.0f + EPSV);
            c1[r] = D;
            c2[r] = D * D;
        }
    }
}

// ---------------- fused mid: [0,2048) = gemm64 (scaled), [2048,10240) = deg ----------------
__global__ __launch_bounds__(256) void k_mid(const unsigned short* __restrict__ adj,
                                             const int* __restrict__ cnt,
                                             const float* __restrict__ nm,
                                             float* __restrict__ c1, float* __restrict__ c2,
                                             const float* __restrict__ Xin,
                                             const float* __restrict__ W,
                                             const float* __restrict__ y,
                                             float* __restrict__ T) {
    int tid = threadIdx.x;
    if (blockIdx.x < 2048) {
        __shared__ __align__(16) float Wl[64 * 64];
        __shared__ float xl[16][65];
        __shared__ float sscale[16];
        int b = blockIdx.x & 31;            // graph -> XCD b%8 (matches spmm reader)
        int cch = blockIdx.x >> 5;
        int row0 = (b << 10) + cch * 16;
        if (tid < 16) {
            int r = row0 + tid;
            sscale[tid] = tanhf(y[r]) * nm[r];
        }
        for (int t = tid; t < 64 * 64; t += 256) Wl[t] = W[t];
        __syncthreads();
        for (int t = tid; t < 16 * 64; t += 256) {
            int rr = t >> 6, kk = t & 63;
            xl[rr][kk] = Xin[(size_t)(row0 + rr) * 64 + kk] * sscale[rr];
        }
        __syncthreads();
        int wave = tid >> 6, lane = tid & 63;
        int rsub = lane >> 4, f0 = (lane & 15) * 4;
        int r = wave * 4 + rsub;
        float4 acc = {0.f, 0.f, 0.f, 0.f};
        const float* xr = xl[r];
#pragma unroll 8
        for (int k = 0; k < 64; ++k) {
            float xv = xr[k];
            float4 w4 = *(const float4*)&Wl[k * 64 + f0];
            acc.x += xv * w4.x; acc.y += xv * w4.y;
            acc.z += xv * w4.z; acc.w += xv * w4.w;
        }
        *(float4*)&T[(size_t)(row0 + r) * 64 + f0] = acc;
    } else {
        // ---- masked degree, wave per row (nm entries are 0/1 -> order-exact) ----
        int wave = tid >> 6, lane = tid & 63;
        int r = (blockIdx.x - 2048) * 4 + wave;
        int b = r >> 10;
        const unsigned short* arow = adj + (size_t)r * CAP;
        const float* nmb = nm + (b << 10);
        int n = cnt[r];
        float s = 0.f;
        if (lane < n)      s  = nmb[arow[lane]];
        if (lane + 64 < n) s += nmb[arow[lane + 64]];
        for (int sh = 32; sh; sh >>= 1) s += __shfl_xor(s, sh, 64);
        if (lane == 0) {
            float m = nm[r];
            float D = 1.0f / sqrtf(m * s + 1.0f + EPSV);
            c1[r] = m * D;
            c2[r] = D * D;
        }
    }
}

// ---------------- SpMM + self + bias + relu (+ fused pool score) ----------------
// XCD swizzle: blockIdx = c*32 + b keeps graph b's T gathers on XCD b%8's L2.
// c1 staged in LDS (broadcast reads, free). 4-unrolled independent gather chains.
__global__ __launch_bounds__(256) void k_spmm(const unsigned short* __restrict__ adj,
                                              const int* __restrict__ cnt,
                                              const float* __restrict__ c1,
                                              const float* __restrict__ c2,
                                              const float* __restrict__ T,
                                              const float* __restrict__ bias,
                                              float* __restrict__ X,
                                              const float* __restrict__ p,
                                              float* __restrict__ y) {
    __shared__ __align__(16) float c1s[NN];
    int b   = blockIdx.x & 31;            // graph
    int cch = blockIdx.x >> 5;            // chunk in [0,256)
    int tid = threadIdx.x;
    ((float4*)c1s)[tid] = ((const float4*)(c1 + (b << 10)))[tid];
    __syncthreads();
    int wave = tid >> 6, lane = tid & 63;
    int r = (b << 10) + cch * 4 + wave;
    const unsigned short* arow = adj + (size_t)r * CAP;
    int n = cnt[r];
    const float* Tb = T + ((size_t)(b << 10) << 6);
    float acc0 = 0.f, acc1 = 0.f, acc2 = 0.f, acc3 = 0.f;
    int t = 0;
    for (; t + 4 <= n; t += 4) {
        ushort4 j4 = *(const ushort4*)(arow + t);
        acc0 += c1s[j4.x] * Tb[((int)j4.x << 6) + lane];
        acc1 += c1s[j4.y] * Tb[((int)j4.y << 6) + lane];
        acc2 += c1s[j4.z] * Tb[((int)j4.z << 6) + lane];
        acc3 += c1s[j4.w] * Tb[((int)j4.w << 6) + lane];
    }
    for (; t < n; ++t) {
        int j = arow[t];
        acc0 += c1s[j] * Tb[(j << 6) + lane];
    }
    float acc = (acc0 + acc1) + (acc2 + acc3);
    int rl = r & 1023;
    float o = c1s[rl] * acc + c2[r] * T[((size_t)r << 6) + lane] + bias[lane];
    o = fmaxf(o, 0.f);
    X[((size_t)r << 6) + lane] = o;
    if (p != nullptr) {
        float pv = p[lane];
        float a = o * pv;
        float pp = pv * pv;
        for (int s = 32; s; s >>= 1) {
            a += __shfl_xor(a, s, 64);
            pp += __shfl_xor(pp, s, 64);
        }
        if (lane == 0) y[r] = a / sqrtf(pp);
    }
}

// ---------------- pool ranking: stable-argsort semantics, 16 blocks/graph ----------------
__global__ __launch_bounds__(256) void k_rank(const float* __restrict__ y,
                                              const float* __restrict__ maskSrc,
                                              const int* __restrict__ nsrc,
                                              float* __restrict__ nmOut,
                                              int* __restrict__ ncur) {
    __shared__ __align__(16) float yv[NN];
    int b = blockIdx.x >> 4;       // 16 blocks per graph
    int sub = blockIdx.x & 15;
    int tid = threadIdx.x;
    const float INF = __builtin_inff();
    {
        float4 v = ((const float4*)(y + (b << 10)))[tid];
        float4 m = ((const float4*)(maskSrc + (b << 10)))[tid];
        v.x = (m.x > 0.f) ? v.x : INF;
        v.y = (m.y > 0.f) ? v.y : INF;
        v.z = (m.z > 0.f) ? v.z : INF;
        v.w = (m.w > 0.f) ? v.w : INF;
        ((float4*)yv)[tid] = v;
    }
    int n = nsrc[b];
    const float RM = (float)(1.0 - 0.8);   // 0.2f, matches jax f32 semantics
    int nrem = (int)((float)n * RM);
    if (sub == 0 && tid == 0) ncur[b] = n - nrem;
    __syncthreads();
    int i = (sub << 6) + (tid >> 2);       // 64 nodes per block, 4 threads per node
    int q = tid & 3;                       // quarter of the j-range
    float yi = yv[i];
    int rank = 0;
    if (yi < INF) {
        const float4* jbase = (const float4*)yv + (q << 6);
        int j0 = q << 8;
#pragma unroll 8
        for (int t = 0; t < 64; ++t) {
            float4 a = jbase[t];
            int j = j0 + t * 4;
            rank += (a.x < yi || (a.x == yi && j     < i)) ? 1 : 0;
            rank += (a.y < yi || (a.y == yi && j + 1 < i)) ? 1 : 0;
            rank += (a.z < yi || (a.z == yi && j + 2 < i)) ? 1 : 0;
            rank += (a.w < yi || (a.w == yi && j + 3 < i)) ? 1 : 0;
        }
    }
    rank += __shfl_xor(rank, 1, 64);
    rank += __shfl_xor(rank, 2, 64);
    if (q == 0) {
        float nmv = (yi < INF && rank >= nrem) ? 1.f : 0.f;
        nmOut[(b << 10) + i] = nmv;
    }
}

// ---------------- global max over nodes + final fc (block b -> XCD b%8, matches X writer) ----------------
__global__ __launch_bounds__(256) void k_final(const float* __restrict__ X,
                                               const float* __restrict__ Wfc,
                                               const float* __restrict__ bfc,
                                               float* __restrict__ out) {
    __shared__ float red[4][64];
    __shared__ float gl[64];
    int b = blockIdx.x, tid = threadIdx.x;
    int f = tid & 63, c = tid >> 6;
    float m = 0.f;  // all values are post-relu >= 0
    for (int i = c; i < NN; i += 4)
        m = fmaxf(m, X[(((size_t)(b << 10) + i) << 6) + f]);
    red[c][f] = m;
    __syncthreads();
    if (tid < 64)
        gl[tid] = fmaxf(fmaxf(red[0][tid], red[1][tid]), fmaxf(red[2][tid], red[3][tid]));
    __syncthreads();
    if (tid < NOUT) {
        float acc = bfc[tid];
        for (int k = 0; k < 64; ++k) acc += gl[k] * Wfc[k * NOUT + tid];
        out[b * NOUT + tid] = acc;
    }
}

extern "C" void kernel_launch(void* const* d_in, const int* in_sizes, int n_in,
                              void* d_out, int out_size, void* d_ws, size_t ws_size,
                              hipStream_t stream) {
    const float* x    = (const float*)d_in[0];
    const float* A    = (const float*)d_in[1];
    const float* mask = (const float*)d_in[2];
    const int*   Nn   = (const int*)d_in[3];
    const float* W0   = (const float*)d_in[4];
    const float* b0   = (const float*)d_in[5];
    const float* W1   = (const float*)d_in[6];
    const float* b1   = (const float*)d_in[7];
    const float* W2   = (const float*)d_in[8];
    const float* b2   = (const float*)d_in[9];
    const float* p0   = (const float*)d_in[10];
    const float* p1   = (const float*)d_in[11];
    const float* Wfc  = (const float*)d_in[12];
    const float* bfc  = (const float*)d_in[13];
    float* out = (float*)d_out;

    char* ws = (char*)d_ws;
    size_t off = 0;
    auto alloc = [&](size_t bytes) -> void* {
        void* p = ws + off;
        off = (off + bytes + 255) & ~(size_t)255;
        return p;
    };
    unsigned short* adj = (unsigned short*)alloc((size_t)BB * NN * CAP * 2);
    int*   cnt  = (int*)  alloc((size_t)BB * NN * 4);
    float* X    = (float*)alloc((size_t)BB * NN * 64 * 4);
    float* T    = (float*)alloc((size_t)BB * NN * 64 * 4);
    float* c1   = (float*)alloc((size_t)BB * NN * 4);
    float* c2   = (float*)alloc((size_t)BB * NN * 4);
    float* y    = (float*)alloc((size_t)BB * NN * 4);
    float* nm0  = (float*)alloc((size_t)BB * NN * 4);
    float* nm1  = (float*)alloc((size_t)BB * NN * 4);
    int*   nc0  = (int*)  alloc((size_t)BB * 4);
    int*   nc1  = (int*)  alloc((size_t)BB * 4);

    const int RW = BB * NN;       // 32768 rows
    const size_t frontLds = (size_t)(CIN * 64 + 16 * (CIN + 1)) * 4;   // 41 KB
    // 1) fused: x@W0 gemm (2048 blocks, XCD-swizzled) + CSR build + layer-1 coefs
    k_front<<<2048 + RW / 4, 256, frontLds, stream>>>(A, x, W0, adj, cnt, c1, c2, T);
    // 2) layer 1 SpMM (+ pool-1 score), XCD-swizzled
    k_spmm<<<RW / 4, 256, 0, stream>>>(adj, cnt, c1, c2, T, b0, X, p0, y);
    // pool 1
    k_rank<<<BB * 16, 256, 0, stream>>>(y, mask, Nn, nm0, nc0);
    // 3) layer 2: fused deg + gemm
    k_mid<<<2048 + RW / 4, 256, 0, stream>>>(adj, cnt, nm0, c1, c2, X, W1, y, T);
    k_spmm<<<RW / 4, 256, 0, stream>>>(adj, cnt, c1, c2, T, b1, X, p1, y);
    // pool 2 (double-buffered mask)
    k_rank<<<BB * 16, 256, 0, stream>>>(y, nm0, nc0, nm1, nc1);
    // 4) layer 3: fused deg + gemm
    k_mid<<<2048 + RW / 4, 256, 0, stream>>>(adj, cnt, nm1, c1, c2, X, W2, y, T);
    k_spmm<<<RW / 4, 256, 0, stream>>>(adj, cnt, c1, c2, T, b2, X, nullptr, nullptr);
    // 5) global max pool + fc
    k_final<<<BB, 256, 0, stream>>>(X, Wfc, bfc, out);
}